// Round 1
// baseline (472.250 us; speedup 1.0000x reference)
//
#include <hip/hip_runtime.h>
#include <math.h>

// Problem constants (MSDeformMatchV2HeaderAttn)
#define BB 2
#define LQ 1024
#define DM 256
#define NH 8
#define DH 32
#define NL 4
#define HWsp 1024   // 32*32
#define LIN 4096
#define K9 36

// ---------------------------------------------------------------------------
// Kernel 1: corr = Q·V^T per (n,h,level); stable running top-4 per (n,h,q,l).
// Softmax skipped (strictly monotone -> identical top-k with stable ties).
// Grid: (16 q-chunks, 4 levels, 16 n*h) x 256 threads.
// ---------------------------------------------------------------------------
#define INSERT4(val, index)                                              \
  {                                                                      \
    const float v_ = (val);                                              \
    const int ix_ = (index);                                             \
    if (v_ > v3) {                                                       \
      if (v_ > v1) {                                                     \
        if (v_ > v0) {                                                   \
          v3 = v2; i3 = i2; v2 = v1; i2 = i1; v1 = v0; i1 = i0;          \
          v0 = v_; i0 = ix_;                                             \
        } else {                                                         \
          v3 = v2; i3 = i2; v2 = v1; i2 = i1; v1 = v_; i1 = ix_;         \
        }                                                                \
      } else {                                                           \
        if (v_ > v2) {                                                   \
          v3 = v2; i3 = i2; v2 = v_; i2 = ix_;                           \
        } else {                                                         \
          v3 = v_; i3 = ix_;                                             \
        }                                                                \
      }                                                                  \
    }                                                                    \
  }

__global__ __launch_bounds__(256) void corr_topk_kernel(
    const float* __restrict__ query, const float* __restrict__ value,
    int* __restrict__ idx_out) {
  __shared__ float qT[32][68];  // [d][q_local], pad 68 -> bank-friendly
  __shared__ float vT[32][68];  // [d][k_local]
  __shared__ float cT[64][68];  // [q_local][k_local]

  const int tid = threadIdx.x;
  const int nh = blockIdx.z;  // n*8+h
  const int n = nh >> 3, h = nh & 7;
  const int l = blockIdx.y;
  const int qb = blockIdx.x << 6;   // 64 queries per block
  const int d = tid & 31, r = tid >> 5;  // loader mapping

  // Stage Q^T once: qT[d][q] = query[n][qb+q][h*32+d]
  {
    const float* qg = query + (size_t)(n * LQ + qb) * DM + h * DH + d;
    #pragma unroll
    for (int i = 0; i < 8; ++i) qT[d][r + (i << 3)] = qg[(size_t)(r + (i << 3)) * DM];
  }

  // top-4 state for the scanning threads (tid<64, one query each)
  float v0 = -INFINITY, v1 = -INFINITY, v2 = -INFINITY, v3 = -INFINITY;
  int i0 = 0, i1 = 0, i2 = 0, i3 = 0;

  const int tk = tid & 15, tq = tid >> 4;
  const float* vgbase = value + (size_t)(n * LIN + l * HWsp) * DM + h * DH + d;

  for (int kc = 0; kc < 16; ++kc) {
    // Stage V^T chunk: vT[d][kk] = value row (kc*64+kk)
    {
      const float* vg = vgbase + (size_t)(kc << 6) * DM;
      #pragma unroll
      for (int i = 0; i < 8; ++i) vT[d][r + (i << 3)] = vg[(size_t)(r + (i << 3)) * DM];
    }
    __syncthreads();  // vT ready; also prev phase-B done reading cT

    // 4x4 register tile: q = qb + 4*tq+i, k = kc*64 + 4*tk+j
    float a00 = 0.f, a01 = 0.f, a02 = 0.f, a03 = 0.f;
    float a10 = 0.f, a11 = 0.f, a12 = 0.f, a13 = 0.f;
    float a20 = 0.f, a21 = 0.f, a22 = 0.f, a23 = 0.f;
    float a30 = 0.f, a31 = 0.f, a32 = 0.f, a33 = 0.f;
    #pragma unroll
    for (int d0 = 0; d0 < 32; ++d0) {
      const float4 qv = *(const float4*)&qT[d0][tq << 2];
      const float4 vv = *(const float4*)&vT[d0][tk << 2];
      a00 = fmaf(qv.x, vv.x, a00); a01 = fmaf(qv.x, vv.y, a01);
      a02 = fmaf(qv.x, vv.z, a02); a03 = fmaf(qv.x, vv.w, a03);
      a10 = fmaf(qv.y, vv.x, a10); a11 = fmaf(qv.y, vv.y, a11);
      a12 = fmaf(qv.y, vv.z, a12); a13 = fmaf(qv.y, vv.w, a13);
      a20 = fmaf(qv.z, vv.x, a20); a21 = fmaf(qv.z, vv.y, a21);
      a22 = fmaf(qv.z, vv.z, a22); a23 = fmaf(qv.z, vv.w, a23);
      a30 = fmaf(qv.w, vv.x, a30); a31 = fmaf(qv.w, vv.y, a31);
      a32 = fmaf(qv.w, vv.z, a32); a33 = fmaf(qv.w, vv.w, a33);
    }
    *(float4*)&cT[(tq << 2) + 0][tk << 2] = make_float4(a00, a01, a02, a03);
    *(float4*)&cT[(tq << 2) + 1][tk << 2] = make_float4(a10, a11, a12, a13);
    *(float4*)&cT[(tq << 2) + 2][tk << 2] = make_float4(a20, a21, a22, a23);
    *(float4*)&cT[(tq << 2) + 3][tk << 2] = make_float4(a30, a31, a32, a33);
    __syncthreads();  // cT ready

    // Phase B: stable top-4 scan (k ascending); strict '>' keeps lower index
    if (tid < 64) {
      const int kb = kc << 6;
      #pragma unroll
      for (int k4 = 0; k4 < 16; ++k4) {
        const float4 c = *(const float4*)&cT[tid][k4 << 2];
        INSERT4(c.x, kb + (k4 << 2) + 0);
        INSERT4(c.y, kb + (k4 << 2) + 1);
        INSERT4(c.z, kb + (k4 << 2) + 2);
        INSERT4(c.w, kb + (k4 << 2) + 3);
      }
    }
  }

  if (tid < 64) {
    // idx_buf layout: [n][h][l][q][4] int32
    ((int4*)idx_out)[(((size_t)nh * NL + l) << 10) + qb + tid] =
        make_int4(i0, i1, i2, i3);
  }
}

// ---------------------------------------------------------------------------
// Kernel 2: loc output. res=clip(idx+delta,0,961); loc=(res>>5, res&31)/32.
// One thread per (n,q,h,l,k9) pair -> writes float2. Exact in fp32.
// ---------------------------------------------------------------------------
__global__ __launch_bounds__(256) void loc_kernel(const int* __restrict__ idx_buf,
                                                  float* __restrict__ loc) {
  const int t = blockIdx.x * 256 + threadIdx.x;  // < 2359296
  const int k = t % 36;
  int rest = t / 36;
  const int l = rest & 3; rest >>= 2;
  const int h = rest & 7; rest >>= 3;
  const int q = rest & 1023;
  const int n = rest >> 10;
  const int p = k & 3, dd = k >> 2;  // delta-major: k = dd*4 + p
  const int idx = idx_buf[(((((n << 3) + h) * NL + l) << 10) + q) * 4 + p];
  const int delta = ((dd / 3) - 1) * 32 + (dd % 3) - 1;  // {-33,-32,-31,-1,0,1,31,32,33}
  int res = idx + delta;
  res = min(max(res, 0), 961);
  const int W = res >> 5, H = res & 31;
  ((float2*)loc)[t] = make_float2((float)W * 0.03125f, (float)H * 0.03125f);
}

// ---------------------------------------------------------------------------
// Kernel 3: gather+average. All bilinear weights are exactly 0.25; corners of
// cell (H=res&31, W=res>>5) are flat {g, g-1, g-32, g-33}, g = H*32+W, gated
// by W>=1 / H>=1. acc = (1/576) * sum. One block per (n,q); thread=(h,d).
// ---------------------------------------------------------------------------
__global__ __launch_bounds__(256) void gather_kernel(
    const float* __restrict__ value, const int* __restrict__ idx_buf,
    float* __restrict__ acc_out) {
  const int nq = blockIdx.x;  // n*1024+q
  const int n = nq >> 10, q = nq & 1023;
  const int tid = threadIdx.x;
  const int h = tid >> 5, d = tid & 31;
  float acc = 0.f;
  #pragma unroll
  for (int l = 0; l < NL; ++l) {
    const int4 id4 =
        ((const int4*)idx_buf)[((((size_t)((n << 3) + h)) * NL + l) << 10) + q];
    const float* vb = value + (size_t)(n * LIN + l * HWsp) * DM + h * DH + d;
    #pragma unroll
    for (int dy = -1; dy <= 1; ++dy) {
      #pragma unroll
      for (int dx = -1; dx <= 1; ++dx) {
        const int delta = dy * 32 + dx;
        #pragma unroll
        for (int p = 0; p < 4; ++p) {
          int res = (p == 0 ? id4.x : p == 1 ? id4.y : p == 2 ? id4.z : id4.w) + delta;
          res = min(max(res, 0), 961);
          const int W = res >> 5, H = res & 31;
          const int g = (H << 5) + W;
          float s = vb[(size_t)g * DM];
          if (W >= 1) s += vb[(size_t)(g - 1) * DM];
          if (H >= 1) s += vb[(size_t)(g - 32) * DM];
          if (W >= 1 && H >= 1) s += vb[(size_t)(g - 33) * DM];
          acc += s;
        }
      }
    }
  }
  acc_out[(size_t)nq * DM + tid] = acc * (1.0f / 576.0f);
}

// ---------------------------------------------------------------------------
// Kernel 4: out = acc @ W^T + b.  256 blocks x 256 threads, 8 q-rows/block.
// ---------------------------------------------------------------------------
__global__ __launch_bounds__(256) void proj_kernel(
    const float* __restrict__ acc_in, const float* __restrict__ W,
    const float* __restrict__ bias, float* __restrict__ out) {
  __shared__ float la[8][256];
  const int qb = blockIdx.x << 3;
  const int tid = threadIdx.x;
  for (int i = tid; i < 8 * 256; i += 256)
    la[i >> 8][i & 255] = acc_in[((size_t)qb << 8) + i];
  __syncthreads();
  const float* wrow = W + (size_t)tid * 256;
  float s0 = 0.f, s1 = 0.f, s2 = 0.f, s3 = 0.f, s4 = 0.f, s5 = 0.f, s6 = 0.f, s7 = 0.f;
  for (int c0 = 0; c0 < 256; c0 += 4) {
    const float4 wv = *(const float4*)(wrow + c0);
    #define PROJ_STEP(qi, sreg)                                   \
      {                                                           \
        const float4 av = *(const float4*)&la[qi][c0];            \
        sreg = fmaf(wv.x, av.x, sreg);                            \
        sreg = fmaf(wv.y, av.y, sreg);                            \
        sreg = fmaf(wv.z, av.z, sreg);                            \
        sreg = fmaf(wv.w, av.w, sreg);                            \
      }
    PROJ_STEP(0, s0) PROJ_STEP(1, s1) PROJ_STEP(2, s2) PROJ_STEP(3, s3)
    PROJ_STEP(4, s4) PROJ_STEP(5, s5) PROJ_STEP(6, s6) PROJ_STEP(7, s7)
    #undef PROJ_STEP
  }
  const float bj = bias[tid];
  out[(size_t)(qb + 0) * 256 + tid] = s0 + bj;
  out[(size_t)(qb + 1) * 256 + tid] = s1 + bj;
  out[(size_t)(qb + 2) * 256 + tid] = s2 + bj;
  out[(size_t)(qb + 3) * 256 + tid] = s3 + bj;
  out[(size_t)(qb + 4) * 256 + tid] = s4 + bj;
  out[(size_t)(qb + 5) * 256 + tid] = s5 + bj;
  out[(size_t)(qb + 6) * 256 + tid] = s6 + bj;
  out[(size_t)(qb + 7) * 256 + tid] = s7 + bj;
}

// ---------------------------------------------------------------------------
extern "C" void kernel_launch(void* const* d_in, const int* in_sizes, int n_in,
                              void* d_out, int out_size, void* d_ws, size_t ws_size,
                              hipStream_t stream) {
  (void)in_sizes; (void)n_in; (void)out_size; (void)ws_size;
  const float* query = (const float*)d_in[0];
  // d_in[1] reference_points: unused by the reference math
  const float* value = (const float*)d_in[2];
  // d_in[3], d_in[4]: spatial shapes / level start (int64) -- constants here
  const float* opw = (const float*)d_in[5];
  const float* opb = (const float*)d_in[6];

  float* out = (float*)d_out;                       // [2,1024,256]
  float* loc = out + (size_t)BB * LQ * DM;          // [2,1024,8,4,36,2]

  int* idx_buf = (int*)d_ws;                                        // 1 MB
  float* acc_buf = (float*)((char*)d_ws + (size_t)BB * NH * NL * LQ * 4 * sizeof(int));

  corr_topk_kernel<<<dim3(16, NL, BB * NH), 256, 0, stream>>>(query, value, idx_buf);
  loc_kernel<<<dim3((BB * LQ * NH * NL * K9) / 256), 256, 0, stream>>>(idx_buf, loc);
  gather_kernel<<<dim3(BB * LQ), 256, 0, stream>>>(value, idx_buf, acc_buf);
  proj_kernel<<<dim3(BB * LQ / 8), 256, 0, stream>>>(acc_buf, opw, opb, out);
}

// Round 2
// 229.984 us; speedup vs baseline: 2.0534x; 2.0534x over previous
//
#include <hip/hip_runtime.h>
#include <math.h>

// Problem constants (MSDeformMatchV2HeaderAttn)
#define BB 2
#define LQ 1024
#define DM 256
#define NH 8
#define DH 32
#define NL 4
#define HWsp 1024   // 32*32
#define LIN 4096
#define K9 36

// ---------------------------------------------------------------------------
// Kernel 1: corr = Q·V^T per (n,h,level); stable running top-4 per (n,h,q,l).
// Softmax skipped (strictly monotone -> identical top-k with stable ties).
// Grid: (16 q-chunks, 4 levels, 16 n*h) x 256 threads.
// ---------------------------------------------------------------------------
#define INSERT4(val, index)                                              \
  {                                                                      \
    const float v_ = (val);                                              \
    const int ix_ = (index);                                             \
    if (v_ > v3) {                                                       \
      if (v_ > v1) {                                                     \
        if (v_ > v0) {                                                   \
          v3 = v2; i3 = i2; v2 = v1; i2 = i1; v1 = v0; i1 = i0;          \
          v0 = v_; i0 = ix_;                                             \
        } else {                                                         \
          v3 = v2; i3 = i2; v2 = v1; i2 = i1; v1 = v_; i1 = ix_;         \
        }                                                                \
      } else {                                                           \
        if (v_ > v2) {                                                   \
          v3 = v2; i3 = i2; v2 = v_; i2 = ix_;                           \
        } else {                                                         \
          v3 = v_; i3 = ix_;                                             \
        }                                                                \
      }                                                                  \
    }                                                                    \
  }

__global__ __launch_bounds__(256) void corr_topk_kernel(
    const float* __restrict__ query, const float* __restrict__ value,
    int* __restrict__ idx_out) {
  __shared__ float qT[32][68];  // [d][q_local], pad 68 -> bank-friendly
  __shared__ float vT[32][68];  // [d][k_local]
  __shared__ float cT[64][68];  // [q_local][k_local]

  const int tid = threadIdx.x;
  const int nh = blockIdx.z;  // n*8+h
  const int n = nh >> 3, h = nh & 7;
  const int l = blockIdx.y;
  const int qb = blockIdx.x << 6;   // 64 queries per block
  const int d = tid & 31, r = tid >> 5;  // loader mapping

  // Stage Q^T once: qT[d][q] = query[n][qb+q][h*32+d]
  {
    const float* qg = query + (size_t)(n * LQ + qb) * DM + h * DH + d;
    #pragma unroll
    for (int i = 0; i < 8; ++i) qT[d][r + (i << 3)] = qg[(size_t)(r + (i << 3)) * DM];
  }

  // top-4 state for the scanning threads (tid<64, one query each)
  float v0 = -INFINITY, v1 = -INFINITY, v2 = -INFINITY, v3 = -INFINITY;
  int i0 = 0, i1 = 0, i2 = 0, i3 = 0;

  const int tk = tid & 15, tq = tid >> 4;
  const float* vgbase = value + (size_t)(n * LIN + l * HWsp) * DM + h * DH + d;

  for (int kc = 0; kc < 16; ++kc) {
    // Stage V^T chunk: vT[d][kk] = value row (kc*64+kk)
    {
      const float* vg = vgbase + (size_t)(kc << 6) * DM;
      #pragma unroll
      for (int i = 0; i < 8; ++i) vT[d][r + (i << 3)] = vg[(size_t)(r + (i << 3)) * DM];
    }
    __syncthreads();  // vT ready; also prev phase-B done reading cT

    // 4x4 register tile: q = qb + 4*tq+i, k = kc*64 + 4*tk+j
    float a00 = 0.f, a01 = 0.f, a02 = 0.f, a03 = 0.f;
    float a10 = 0.f, a11 = 0.f, a12 = 0.f, a13 = 0.f;
    float a20 = 0.f, a21 = 0.f, a22 = 0.f, a23 = 0.f;
    float a30 = 0.f, a31 = 0.f, a32 = 0.f, a33 = 0.f;
    #pragma unroll
    for (int d0 = 0; d0 < 32; ++d0) {
      const float4 qv = *(const float4*)&qT[d0][tq << 2];
      const float4 vv = *(const float4*)&vT[d0][tk << 2];
      a00 = fmaf(qv.x, vv.x, a00); a01 = fmaf(qv.x, vv.y, a01);
      a02 = fmaf(qv.x, vv.z, a02); a03 = fmaf(qv.x, vv.w, a03);
      a10 = fmaf(qv.y, vv.x, a10); a11 = fmaf(qv.y, vv.y, a11);
      a12 = fmaf(qv.y, vv.z, a12); a13 = fmaf(qv.y, vv.w, a13);
      a20 = fmaf(qv.z, vv.x, a20); a21 = fmaf(qv.z, vv.y, a21);
      a22 = fmaf(qv.z, vv.z, a22); a23 = fmaf(qv.z, vv.w, a23);
      a30 = fmaf(qv.w, vv.x, a30); a31 = fmaf(qv.w, vv.y, a31);
      a32 = fmaf(qv.w, vv.z, a32); a33 = fmaf(qv.w, vv.w, a33);
    }
    *(float4*)&cT[(tq << 2) + 0][tk << 2] = make_float4(a00, a01, a02, a03);
    *(float4*)&cT[(tq << 2) + 1][tk << 2] = make_float4(a10, a11, a12, a13);
    *(float4*)&cT[(tq << 2) + 2][tk << 2] = make_float4(a20, a21, a22, a23);
    *(float4*)&cT[(tq << 2) + 3][tk << 2] = make_float4(a30, a31, a32, a33);
    __syncthreads();  // cT ready

    // Phase B: stable top-4 scan (k ascending); strict '>' keeps lower index
    if (tid < 64) {
      const int kb = kc << 6;
      #pragma unroll
      for (int k4 = 0; k4 < 16; ++k4) {
        const float4 c = *(const float4*)&cT[tid][k4 << 2];
        INSERT4(c.x, kb + (k4 << 2) + 0);
        INSERT4(c.y, kb + (k4 << 2) + 1);
        INSERT4(c.z, kb + (k4 << 2) + 2);
        INSERT4(c.w, kb + (k4 << 2) + 3);
      }
    }
  }

  if (tid < 64) {
    // idx_buf layout: [n][h][l][q][4] int32
    ((int4*)idx_out)[(((size_t)nh * NL + l) << 10) + qb + tid] =
        make_int4(i0, i1, i2, i3);
  }
}

// ---------------------------------------------------------------------------
// Kernel 2: loc output. res=clip(idx+delta,0,961); loc=(res>>5, res&31)/32.
// One thread per (n,q,h,l,k9) pair -> writes float2. Exact in fp32.
// ---------------------------------------------------------------------------
__global__ __launch_bounds__(256) void loc_kernel(const int* __restrict__ idx_buf,
                                                  float* __restrict__ loc) {
  const int t = blockIdx.x * 256 + threadIdx.x;  // < 2359296
  const int k = t % 36;
  int rest = t / 36;
  const int l = rest & 3; rest >>= 2;
  const int h = rest & 7; rest >>= 3;
  const int q = rest & 1023;
  const int n = rest >> 10;
  const int p = k & 3, dd = k >> 2;  // delta-major: k = dd*4 + p
  const int idx = idx_buf[(((((n << 3) + h) * NL + l) << 10) + q) * 4 + p];
  const int delta = ((dd / 3) - 1) * 32 + (dd % 3) - 1;  // {-33,-32,-31,-1,0,1,31,32,33}
  int res = idx + delta;
  res = min(max(res, 0), 961);
  const int W = res >> 5, H = res & 31;
  ((float2*)loc)[t] = make_float2((float)W * 0.03125f, (float)H * 0.03125f);
}

// ---------------------------------------------------------------------------
// Kernel 3: gather+average. All bilinear weights are exactly 0.25; corners of
// cell (H=res&31, W=res>>5) are rows {g, g-1, g-32, g-33}, g = H*32+W, gated
// by W>=1 / H>=1 (gates applied as 0/1 weights, addresses clamped to >=0 so
// loads are unconditional and exec-full -> no divergence).
// Block = (n,q); thread = (l, h, d4): wave = one level; float4 per lane ->
// 1 KiB per load instruction; 144 independent loads per thread.
// LDS reduction over the 4 levels at the end. acc = (1/576) * sum.
// ---------------------------------------------------------------------------
__global__ __launch_bounds__(256) void gather_kernel(
    const float* __restrict__ value, const int* __restrict__ idx_buf,
    float* __restrict__ acc_out) {
  __shared__ float red[NL][DM];
  const int nq = blockIdx.x;  // n*1024+q
  const int n = nq >> 10, q = nq & 1023;
  const int tid = threadIdx.x;
  const int l = tid >> 6;          // wave index = level
  const int h = (tid >> 3) & 7;
  const int d4 = tid & 7;          // float4 lane within the 32-float head dim

  const int4 id4 =
      ((const int4*)idx_buf)[((((size_t)((n << 3) + h)) * NL + l) << 10) + q];

  // base: value[n][l*1024 + row][h*32 + d4*4 ..], row stride = 64 float4
  const float4* vb4 =
      (const float4*)(value + (size_t)(n * LIN + l * HWsp) * DM + h * DH) + d4;

  float4 a = make_float4(0.f, 0.f, 0.f, 0.f);
  #pragma unroll
  for (int p = 0; p < 4; ++p) {
    const int idx = (p == 0) ? id4.x : (p == 1) ? id4.y : (p == 2) ? id4.z : id4.w;
    #pragma unroll
    for (int dy = -1; dy <= 1; ++dy) {
      #pragma unroll
      for (int dx = -1; dx <= 1; ++dx) {
        int res = idx + dy * 32 + dx;
        res = min(max(res, 0), 961);
        const int W = res >> 5, H = res & 31;
        const int g = (H << 5) + W;
        const float wW = (W >= 1) ? 1.f : 0.f;
        const float wH = (H >= 1) ? 1.f : 0.f;
        const float wB = wW * wH;
        const float4 c0 = vb4[(size_t)g * 64];
        const float4 c1 = vb4[(size_t)max(g - 1, 0) * 64];
        const float4 c2 = vb4[(size_t)max(g - 32, 0) * 64];
        const float4 c3 = vb4[(size_t)max(g - 33, 0) * 64];
        a.x += c0.x + wW * c1.x + wH * c2.x + wB * c3.x;
        a.y += c0.y + wW * c1.y + wH * c2.y + wB * c3.y;
        a.z += c0.z + wW * c1.z + wH * c2.z + wB * c3.z;
        a.w += c0.w + wW * c1.w + wH * c2.w + wB * c3.w;
      }
    }
  }

  const int col = h * DH + d4 * 4;
  red[l][col + 0] = a.x;
  red[l][col + 1] = a.y;
  red[l][col + 2] = a.z;
  red[l][col + 3] = a.w;
  __syncthreads();
  const float s = red[0][tid] + red[1][tid] + red[2][tid] + red[3][tid];
  acc_out[(size_t)nq * DM + tid] = s * (1.0f / 576.0f);
}

// ---------------------------------------------------------------------------
// Kernel 4: out = acc @ W^T + b.  256 blocks x 256 threads, 8 q-rows/block.
// ---------------------------------------------------------------------------
__global__ __launch_bounds__(256) void proj_kernel(
    const float* __restrict__ acc_in, const float* __restrict__ W,
    const float* __restrict__ bias, float* __restrict__ out) {
  __shared__ float la[8][256];
  const int qb = blockIdx.x << 3;
  const int tid = threadIdx.x;
  for (int i = tid; i < 8 * 256; i += 256)
    la[i >> 8][i & 255] = acc_in[((size_t)qb << 8) + i];
  __syncthreads();
  const float* wrow = W + (size_t)tid * 256;
  float s0 = 0.f, s1 = 0.f, s2 = 0.f, s3 = 0.f, s4 = 0.f, s5 = 0.f, s6 = 0.f, s7 = 0.f;
  for (int c0 = 0; c0 < 256; c0 += 4) {
    const float4 wv = *(const float4*)(wrow + c0);
    #define PROJ_STEP(qi, sreg)                                   \
      {                                                           \
        const float4 av = *(const float4*)&la[qi][c0];            \
        sreg = fmaf(wv.x, av.x, sreg);                            \
        sreg = fmaf(wv.y, av.y, sreg);                            \
        sreg = fmaf(wv.z, av.z, sreg);                            \
        sreg = fmaf(wv.w, av.w, sreg);                            \
      }
    PROJ_STEP(0, s0) PROJ_STEP(1, s1) PROJ_STEP(2, s2) PROJ_STEP(3, s3)
    PROJ_STEP(4, s4) PROJ_STEP(5, s5) PROJ_STEP(6, s6) PROJ_STEP(7, s7)
    #undef PROJ_STEP
  }
  const float bj = bias[tid];
  out[(size_t)(qb + 0) * 256 + tid] = s0 + bj;
  out[(size_t)(qb + 1) * 256 + tid] = s1 + bj;
  out[(size_t)(qb + 2) * 256 + tid] = s2 + bj;
  out[(size_t)(qb + 3) * 256 + tid] = s3 + bj;
  out[(size_t)(qb + 4) * 256 + tid] = s4 + bj;
  out[(size_t)(qb + 5) * 256 + tid] = s5 + bj;
  out[(size_t)(qb + 6) * 256 + tid] = s6 + bj;
  out[(size_t)(qb + 7) * 256 + tid] = s7 + bj;
}

// ---------------------------------------------------------------------------
extern "C" void kernel_launch(void* const* d_in, const int* in_sizes, int n_in,
                              void* d_out, int out_size, void* d_ws, size_t ws_size,
                              hipStream_t stream) {
  (void)in_sizes; (void)n_in; (void)out_size; (void)ws_size;
  const float* query = (const float*)d_in[0];
  // d_in[1] reference_points: unused by the reference math
  const float* value = (const float*)d_in[2];
  // d_in[3], d_in[4]: spatial shapes / level start (int64) -- constants here
  const float* opw = (const float*)d_in[5];
  const float* opb = (const float*)d_in[6];

  float* out = (float*)d_out;                       // [2,1024,256]
  float* loc = out + (size_t)BB * LQ * DM;          // [2,1024,8,4,36,2]

  int* idx_buf = (int*)d_ws;                                        // 1 MB
  float* acc_buf = (float*)((char*)d_ws + (size_t)BB * NH * NL * LQ * 4 * sizeof(int));

  corr_topk_kernel<<<dim3(16, NL, BB * NH), 256, 0, stream>>>(query, value, idx_buf);
  loc_kernel<<<dim3((BB * LQ * NH * NL * K9) / 256), 256, 0, stream>>>(idx_buf, loc);
  gather_kernel<<<dim3(BB * LQ), 256, 0, stream>>>(value, idx_buf, acc_buf);
  proj_kernel<<<dim3(BB * LQ / 8), 256, 0, stream>>>(acc_buf, opw, opb, out);
}